// Round 1
// baseline (1272.698 us; speedup 1.0000x reference)
//
#include <hip/hip_runtime.h>
#include <math.h>

#define N_NODES 50000
#define N_EDGES 600000

constexpr float RS          = 1.6765324703310907f;
constexpr float INV_SQRT8   = 0.35355339059327373f;
constexpr float INV8        = 0.125f;
constexpr float INV_SQRT320 = 0.05590169943749474f;
constexpr float INV_SQRT32  = 0.17677669529663687f;
constexpr float INV_SQRT96  = 0.10206207261596575f;
constexpr float INV_AVG     = 1.0f / 12.0f;

// ws layout (bytes)
constexpr size_t OFF_X   = 0;           // N*32 float4 = 25,600,000
constexpr size_t OFF_ROW = 25600000;    // (N+1) int   =    200,004
constexpr size_t OFF_W2T = 25800192;    // 64*64 float =     16,384
constexpr size_t OFF_W   = 25816576;    // E*160 bf16  = 192,000,000

__device__ __forceinline__ float rsilu(float z) {
  return RS * z / (1.0f + __expf(-z));
}
__device__ __forceinline__ unsigned short f2bf(float x) {
  unsigned u = __float_as_uint(x);
  u += 0x7FFFu + ((u >> 16) & 1u);
  return (unsigned short)(u >> 16);
}
__device__ __forceinline__ float bf2f(unsigned short u) {
  return __uint_as_float(((unsigned)u) << 16);
}

// ---------------- CSR row offsets from sorted idx_i ----------------
__global__ __launch_bounds__(256) void k_rowstart(const int* __restrict__ idx_i,
                                                  int* __restrict__ row,
                                                  int E, int N) {
  int e = blockIdx.x * 256 + threadIdx.x;
  if (e >= E) return;
  int cur  = idx_i[e];
  int prev = (e == 0) ? -1 : idx_i[e - 1];
  for (int n = prev + 1; n <= cur; ++n) row[n] = e;
  if (e == E - 1) {
    for (int n = cur + 1; n <= N; ++n) row[n] = E;
  }
}

// ---------------- transpose Wr2 (64x64) ----------------
__global__ __launch_bounds__(256) void k_transpose64(const float* __restrict__ W,
                                                     float* __restrict__ WT) {
  int t = blockIdx.x * 256 + threadIdx.x;   // 4096 threads
  int d = t >> 6, j = t & 63;
  WT[j * 64 + d] = W[d * 64 + j];
}

// ---------------- per-node: sc (skip) + x (first linear) ----------------
__global__ __launch_bounds__(256) void k_node(const float* __restrict__ attrs,
                                              const float* __restrict__ feats,
                                              const float* __restrict__ Wf,
                                              const float* __restrict__ Wsk,
                                              float* __restrict__ out_sc,
                                              float* __restrict__ x_ws) {
  int t = blockIdx.x * 256 + threadIdx.x;   // exactly N*32 threads
  int n = t >> 5, w = t & 31;
  float a[10];
#pragma unroll
  for (int v = 0; v < 10; ++v) a[v] = attrs[n * 10 + v];
  float scm0 = 0.f, scm1 = 0.f, scm2 = 0.f, scm3 = 0.f;
  float x0 = 0.f, x1 = 0.f, x2 = 0.f, x3 = 0.f;
  const float4* f4 = (const float4*)feats + (size_t)n * 32;
#pragma unroll 4
  for (int c = 0; c < 32; ++c) {
    float4 f = f4[c];
    float a0 = 0.f, a1 = 0.f;
#pragma unroll
    for (int v = 0; v < 10; ++v) {
      a0 += a[v] * Wsk[(c * 10 + v) * 32 + w];            // W_skip[0][c][v][w]
      a1 += a[v] * Wsk[((32 + c) * 10 + v) * 32 + w];     // W_skip[1][c][v][w]
    }
    scm0 += f.x * a0; scm1 += f.y * a1; scm2 += f.z * a1; scm3 += f.w * a1;
    float wf0 = Wf[w * 32 + c];            // W_first[0][w][c]
    float wf1 = Wf[1024 + w * 32 + c];     // W_first[1][w][c]
    x0 += f.x * wf0; x1 += f.y * wf1; x2 += f.z * wf1; x3 += f.w * wf1;
  }
  float4 sc = {scm0 * INV_SQRT320, scm1 * INV_SQRT320,
               scm2 * INV_SQRT320, scm3 * INV_SQRT320};
  float4 xx = {x0 * INV_SQRT32, x1 * INV_SQRT32, x2 * INV_SQRT32, x3 * INV_SQRT32};
  ((float4*)out_sc)[(size_t)n * 32 + w] = sc;
  ((float4*)x_ws)[(size_t)n * 32 + w]   = xx;
}

// ---------------- per-edge 4-layer MLP -> w (bf16, E x 160) ----------------
__global__ __launch_bounds__(256) void k_mlp(const float* __restrict__ ef,
                                             const float* __restrict__ Wr0,
                                             const float* __restrict__ Wr1,
                                             const float* __restrict__ W2T,
                                             const float* __restrict__ Wr3,
                                             unsigned short* __restrict__ w_out,
                                             int E) {
  int e = blockIdx.x * 256 + threadIdx.x;
  bool valid = (e < E);
  int ee = valid ? e : (E - 1);

  const float4* efp = (const float4*)ef + (size_t)ee * 2;
  float4 i0 = efp[0], i1 = efp[1];
  float in[8] = {i0.x, i0.y, i0.z, i0.w, i1.x, i1.y, i1.z, i1.w};

  // layer 1 (direct form, fully unrolled: 512 fmac)
  float h1[64];
#pragma unroll
  for (int d = 0; d < 64; ++d) {
    float z = 0.f;
#pragma unroll
    for (int b = 0; b < 8; ++b) z += in[b] * Wr0[d * 8 + b];
    h1[d] = rsilu(z * INV_SQRT8);
  }

  // layers 2+3 fused via loop interchange:
  //   z3[d3] += rsilu(z2(d2)) * Wr2^T[d2][d3]   (all reg arrays statically indexed)
  float z3[64];
#pragma unroll
  for (int d = 0; d < 64; ++d) z3[d] = 0.f;
#pragma unroll 2
  for (int d2 = 0; d2 < 64; ++d2) {
    float z = 0.f;
#pragma unroll
    for (int j = 0; j < 64; ++j) z += h1[j] * Wr1[d2 * 64 + j];   // uniform -> s_load
    float s = rsilu(z * INV8);
#pragma unroll
    for (int d3 = 0; d3 < 64; ++d3) z3[d3] += s * W2T[d2 * 64 + d3];
  }
  float h3[64];
#pragma unroll
  for (int d = 0; d < 64; ++d) h3[d] = rsilu(z3[d] * INV8);

  // layer 4 in chunks of 8 outputs, packed bf16 stores (16B per chunk)
#pragma unroll 1
  for (int r0 = 0; r0 < 160; r0 += 8) {
    float wv[8];
#pragma unroll
    for (int q = 0; q < 8; ++q) {
      float z = 0.f;
#pragma unroll
      for (int j = 0; j < 64; ++j) z += h3[j] * Wr3[(r0 + q) * 64 + j];
      wv[q] = z * INV8;
    }
    if (valid) {
      uint4 pk;
      pk.x = (unsigned)f2bf(wv[0]) | ((unsigned)f2bf(wv[1]) << 16);
      pk.y = (unsigned)f2bf(wv[2]) | ((unsigned)f2bf(wv[3]) << 16);
      pk.z = (unsigned)f2bf(wv[4]) | ((unsigned)f2bf(wv[5]) << 16);
      pk.w = (unsigned)f2bf(wv[6]) | ((unsigned)f2bf(wv[7]) << 16);
      *((uint4*)(w_out + (size_t)ee * 160 + r0)) = pk;
    }
  }
}

// ---------------- per-node message accumulation + W_second contraction ----------------
__global__ __launch_bounds__(256) void k_msg(const unsigned short* __restrict__ w_ws,
                                             const float* __restrict__ x_ws,
                                             const float* __restrict__ ea,
                                             const int* __restrict__ idx_j,
                                             const int* __restrict__ row,
                                             const float* __restrict__ Ws0,
                                             const float* __restrict__ Ws1,
                                             float* __restrict__ out_msg) {
  __shared__ float msg[8][353];     // 352 comps padded (353%32==1 -> conflict-free)
  __shared__ float W0T[64 * 33];    // [k*33+d]
  __shared__ float W1T[96 * 33];

  int tid = threadIdx.x;
  for (int t = tid; t < 2048; t += 256) {     // Ws0 (32x64) -> W0T[k][d]
    int d = t >> 6, k = t & 63;
    W0T[k * 33 + d] = Ws0[t];
  }
  for (int t = tid; t < 3072; t += 256) {     // Ws1 (32x96) -> W1T[k][d]
    int d = t / 96, k = t % 96;
    W1T[k * 33 + d] = Ws1[t];
  }

  int ln = tid >> 5, c = tid & 31;
  int n = blockIdx.x * 8 + ln;                // grid exactly N/8
  int e0 = row[n], e1 = row[n + 1];

  float m00 = 0.f, m01 = 0.f;
  float m10x = 0.f, m10y = 0.f, m10z = 0.f;
  float m11x = 0.f, m11y = 0.f, m11z = 0.f;
  float m12x = 0.f, m12y = 0.f, m12z = 0.f;

  for (int e = e0; e < e1; ++e) {
    int j = idx_j[e];
    float4 xj = ((const float4*)x_ws)[(size_t)j * 32 + c];  // {x0, x1_0, x1_1, x1_2}
    float4 y  = ((const float4*)ea)[e];                     // {y0, y1_0, y1_1, y1_2}
    const unsigned short* wr = w_ws + (size_t)e * 160;
    float w0 = bf2f(wr[c]);
    float w1 = bf2f(wr[32 + c]);
    float w2 = bf2f(wr[64 + c]);
    float w3 = bf2f(wr[96 + c]);
    float w4 = bf2f(wr[128 + c]);
    m00 += w0 * xj.x * y.x;                                   // p0
    m01 += w3 * (xj.y * y.y + xj.z * y.z + xj.w * y.w);       // p3
    m10x += w1 * xj.x * y.y; m10y += w1 * xj.x * y.z; m10z += w1 * xj.x * y.w;  // p1
    m11x += w2 * xj.y * y.x; m11y += w2 * xj.z * y.x; m11z += w2 * xj.w * y.x;  // p2
    float cx = xj.z * y.w - xj.w * y.z;
    float cy = xj.w * y.y - xj.y * y.w;
    float cz = xj.y * y.z - xj.z * y.y;
    m12x += w4 * cx; m12y += w4 * cy; m12z += w4 * cz;        // p4
  }

  msg[ln][c]      = m00;
  msg[ln][32 + c] = m01;
  msg[ln][64 + (0 * 32 + c) * 3 + 0] = m10x;
  msg[ln][64 + (0 * 32 + c) * 3 + 1] = m10y;
  msg[ln][64 + (0 * 32 + c) * 3 + 2] = m10z;
  msg[ln][64 + (1 * 32 + c) * 3 + 0] = m11x;
  msg[ln][64 + (1 * 32 + c) * 3 + 1] = m11y;
  msg[ln][64 + (1 * 32 + c) * 3 + 2] = m11z;
  msg[ln][64 + (2 * 32 + c) * 3 + 0] = m12x;
  msg[ln][64 + (2 * 32 + c) * 3 + 1] = m12y;
  msg[ln][64 + (2 * 32 + c) * 3 + 2] = m12z;
  __syncthreads();

  // out0[n][d=c], out1[n][d=c][m]
  float o0 = 0.f;
#pragma unroll 4
  for (int k = 0; k < 64; ++k) o0 += msg[ln][k] * W0T[k * 33 + c];
  float o1x = 0.f, o1y = 0.f, o1z = 0.f;
#pragma unroll 4
  for (int k = 0; k < 96; ++k) {
    float wv = W1T[k * 33 + c];
    o1x += msg[ln][64 + k * 3 + 0] * wv;
    o1y += msg[ln][64 + k * 3 + 1] * wv;
    o1z += msg[ln][64 + k * 3 + 2] * wv;
  }
  float4 res = {o0 * INV8 * INV_AVG, o1x * INV_SQRT96 * INV_AVG,
                o1y * INV_SQRT96 * INV_AVG, o1z * INV_SQRT96 * INV_AVG};
  ((float4*)out_msg)[(size_t)n * 32 + c] = res;
}

extern "C" void kernel_launch(void* const* d_in, const int* in_sizes, int n_in,
                              void* d_out, int out_size, void* d_ws, size_t ws_size,
                              hipStream_t stream) {
  const float* node_attrs = (const float*)d_in[0];
  const float* node_feats = (const float*)d_in[1];
  const float* edge_attrs = (const float*)d_in[2];
  const float* edge_feats = (const float*)d_in[3];
  const float* W_first    = (const float*)d_in[4];
  const float* Wr0        = (const float*)d_in[5];
  const float* Wr1        = (const float*)d_in[6];
  const float* Wr2        = (const float*)d_in[7];
  const float* Wr3        = (const float*)d_in[8];
  const float* Ws0        = (const float*)d_in[9];
  const float* Ws1        = (const float*)d_in[10];
  const float* Wsk        = (const float*)d_in[11];
  const int*   idx_i      = (const int*)d_in[12];
  const int*   idx_j      = (const int*)d_in[13];
  float* out = (float*)d_out;

  char* ws = (char*)d_ws;
  float*          x_ws = (float*)(ws + OFF_X);
  int*            row  = (int*)(ws + OFF_ROW);
  float*          W2T  = (float*)(ws + OFF_W2T);
  unsigned short* w_ws = (unsigned short*)(ws + OFF_W);

  k_rowstart<<<(N_EDGES + 255) / 256, 256, 0, stream>>>(idx_i, row, N_EDGES, N_NODES);
  k_transpose64<<<16, 256, 0, stream>>>(Wr2, W2T);
  k_node<<<N_NODES / 8, 256, 0, stream>>>(node_attrs, node_feats, W_first, Wsk,
                                          out + 6400000, x_ws);
  k_mlp<<<(N_EDGES + 255) / 256, 256, 0, stream>>>(edge_feats, Wr0, Wr1, W2T, Wr3,
                                                   w_ws, N_EDGES);
  k_msg<<<N_NODES / 8, 256, 0, stream>>>(w_ws, x_ws, edge_attrs, idx_j, row,
                                         Ws0, Ws1, out);
}

// Round 2
// 1261.568 us; speedup vs baseline: 1.0088x; 1.0088x over previous
//
#include <hip/hip_runtime.h>
#include <math.h>

#define N_NODES 50000
#define N_EDGES 600000

constexpr float RS          = 1.6765324703310907f;
constexpr float INV_SQRT8   = 0.35355339059327373f;
constexpr float INV8        = 0.125f;
constexpr float INV_SQRT320 = 0.05590169943749474f;
constexpr float INV_SQRT32  = 0.17677669529663687f;
constexpr float INV_SQRT96  = 0.10206207261596575f;
constexpr float INV_AVG     = 1.0f / 12.0f;

// ws layout (bytes)
constexpr size_t OFF_X   = 0;           // N*32 float4 = 25,600,000
constexpr size_t OFF_ROW = 25600000;    // (N+1) int   =    200,004
constexpr size_t OFF_W2T = 25800192;    // 64*64 float =     16,384
constexpr size_t OFF_W   = 25816576;    // E*160 bf16  = 192,000,000

__device__ __forceinline__ float rsilu(float z) {
  return RS * z / (1.0f + __expf(-z));
}
__device__ __forceinline__ unsigned short f2bf(float x) {
  unsigned u = __float_as_uint(x);
  u += 0x7FFFu + ((u >> 16) & 1u);
  return (unsigned short)(u >> 16);
}
__device__ __forceinline__ float bf2f(unsigned short u) {
  return __uint_as_float(((unsigned)u) << 16);
}

// ---------------- CSR row offsets from sorted idx_i ----------------
__global__ __launch_bounds__(256) void k_rowstart(const int* __restrict__ idx_i,
                                                  int* __restrict__ row,
                                                  int E, int N) {
  int e = blockIdx.x * 256 + threadIdx.x;
  if (e >= E) return;
  int cur  = idx_i[e];
  int prev = (e == 0) ? -1 : idx_i[e - 1];
  for (int n = prev + 1; n <= cur; ++n) row[n] = e;
  if (e == E - 1) {
    for (int n = cur + 1; n <= N; ++n) row[n] = E;
  }
}

// ---------------- transpose Wr2 (64x64) ----------------
__global__ __launch_bounds__(256) void k_transpose64(const float* __restrict__ W,
                                                     float* __restrict__ WT) {
  int t = blockIdx.x * 256 + threadIdx.x;   // 4096 threads
  int d = t >> 6, j = t & 63;
  WT[j * 64 + d] = W[d * 64 + j];
}

// ---------------- per-node: sc (skip) + x (first linear) ----------------
__global__ __launch_bounds__(256) void k_node(const float* __restrict__ attrs,
                                              const float* __restrict__ feats,
                                              const float* __restrict__ Wf,
                                              const float* __restrict__ Wsk,
                                              float* __restrict__ out_sc,
                                              float* __restrict__ x_ws) {
  int t = blockIdx.x * 256 + threadIdx.x;   // exactly N*32 threads
  int n = t >> 5, w = t & 31;
  float a[10];
#pragma unroll
  for (int v = 0; v < 10; ++v) a[v] = attrs[n * 10 + v];
  float scm0 = 0.f, scm1 = 0.f, scm2 = 0.f, scm3 = 0.f;
  float x0 = 0.f, x1 = 0.f, x2 = 0.f, x3 = 0.f;
  const float4* f4 = (const float4*)feats + (size_t)n * 32;
#pragma unroll 4
  for (int c = 0; c < 32; ++c) {
    float4 f = f4[c];
    float a0 = 0.f, a1 = 0.f;
#pragma unroll
    for (int v = 0; v < 10; ++v) {
      a0 += a[v] * Wsk[(c * 10 + v) * 32 + w];            // W_skip[0][c][v][w]
      a1 += a[v] * Wsk[((32 + c) * 10 + v) * 32 + w];     // W_skip[1][c][v][w]
    }
    scm0 += f.x * a0; scm1 += f.y * a1; scm2 += f.z * a1; scm3 += f.w * a1;
    float wf0 = Wf[w * 32 + c];            // W_first[0][w][c]
    float wf1 = Wf[1024 + w * 32 + c];     // W_first[1][w][c]
    x0 += f.x * wf0; x1 += f.y * wf1; x2 += f.z * wf1; x3 += f.w * wf1;
  }
  float4 sc = {scm0 * INV_SQRT320, scm1 * INV_SQRT320,
               scm2 * INV_SQRT320, scm3 * INV_SQRT320};
  float4 xx = {x0 * INV_SQRT32, x1 * INV_SQRT32, x2 * INV_SQRT32, x3 * INV_SQRT32};
  ((float4*)out_sc)[(size_t)n * 32 + w] = sc;
  ((float4*)x_ws)[(size_t)n * 32 + w]   = xx;
}

// ---------------- per-edge 4-layer MLP -> w (bf16, E x 160) ----------------
// __launch_bounds__(256, 2): 2 waves/EU -> 256 VGPR budget per thread.
// Live set is ~150 floats (h1[64] + z3[64] + temps); at the default budget
// (76 VGPRs) the compiler spilled ~540 MB of scratch stores to HBM per
// dispatch (R1 rocprof: WRITE_SIZE 733 MB vs 192 MB of real output).
__global__ __launch_bounds__(256, 2) void k_mlp(const float* __restrict__ ef,
                                                const float* __restrict__ Wr0,
                                                const float* __restrict__ Wr1,
                                                const float* __restrict__ W2T,
                                                const float* __restrict__ Wr3,
                                                unsigned short* __restrict__ w_out,
                                                int E) {
  int e = blockIdx.x * 256 + threadIdx.x;
  bool valid = (e < E);
  int ee = valid ? e : (E - 1);

  const float4* efp = (const float4*)ef + (size_t)ee * 2;
  float4 i0 = efp[0], i1 = efp[1];
  float in[8] = {i0.x, i0.y, i0.z, i0.w, i1.x, i1.y, i1.z, i1.w};

  // layer 1 (direct form, fully unrolled: 512 fmac)
  float h1[64];
#pragma unroll
  for (int d = 0; d < 64; ++d) {
    float z = 0.f;
#pragma unroll
    for (int b = 0; b < 8; ++b) z += in[b] * Wr0[d * 8 + b];
    h1[d] = rsilu(z * INV_SQRT8);
  }

  // layers 2+3 fused via loop interchange:
  //   z3[d3] += rsilu(z2(d2)) * Wr2^T[d2][d3]   (all reg arrays statically indexed)
  float z3[64];
#pragma unroll
  for (int d = 0; d < 64; ++d) z3[d] = 0.f;
#pragma unroll 2
  for (int d2 = 0; d2 < 64; ++d2) {
    float z = 0.f;
#pragma unroll
    for (int j = 0; j < 64; ++j) z += h1[j] * Wr1[d2 * 64 + j];   // uniform -> s_load
    float s = rsilu(z * INV8);
#pragma unroll
    for (int d3 = 0; d3 < 64; ++d3) z3[d3] += s * W2T[d2 * 64 + d3];
  }
  // h3 in place (frees h1's successor pressure; z3 now holds h3)
#pragma unroll
  for (int d = 0; d < 64; ++d) z3[d] = rsilu(z3[d] * INV8);

  // layer 4 in chunks of 8 outputs, packed bf16 stores (16B per chunk)
#pragma unroll 1
  for (int r0 = 0; r0 < 160; r0 += 8) {
    float wv[8];
#pragma unroll
    for (int q = 0; q < 8; ++q) {
      float z = 0.f;
#pragma unroll
      for (int j = 0; j < 64; ++j) z += z3[j] * Wr3[(r0 + q) * 64 + j];
      wv[q] = z * INV8;
    }
    if (valid) {
      uint4 pk;
      pk.x = (unsigned)f2bf(wv[0]) | ((unsigned)f2bf(wv[1]) << 16);
      pk.y = (unsigned)f2bf(wv[2]) | ((unsigned)f2bf(wv[3]) << 16);
      pk.z = (unsigned)f2bf(wv[4]) | ((unsigned)f2bf(wv[5]) << 16);
      pk.w = (unsigned)f2bf(wv[6]) | ((unsigned)f2bf(wv[7]) << 16);
      *((uint4*)(w_out + (size_t)ee * 160 + r0)) = pk;
    }
  }
}

// ---------------- per-node message accumulation + W_second contraction ----------------
__global__ __launch_bounds__(256) void k_msg(const unsigned short* __restrict__ w_ws,
                                             const float* __restrict__ x_ws,
                                             const float* __restrict__ ea,
                                             const int* __restrict__ idx_j,
                                             const int* __restrict__ row,
                                             const float* __restrict__ Ws0,
                                             const float* __restrict__ Ws1,
                                             float* __restrict__ out_msg) {
  __shared__ float msg[8][353];     // 352 comps padded (353%32==1 -> conflict-free)
  __shared__ float W0T[64 * 33];    // [k*33+d]
  __shared__ float W1T[96 * 33];

  int tid = threadIdx.x;
  for (int t = tid; t < 2048; t += 256) {     // Ws0 (32x64) -> W0T[k][d]
    int d = t >> 6, k = t & 63;
    W0T[k * 33 + d] = Ws0[t];
  }
  for (int t = tid; t < 3072; t += 256) {     // Ws1 (32x96) -> W1T[k][d]
    int d = t / 96, k = t % 96;
    W1T[k * 33 + d] = Ws1[t];
  }

  int ln = tid >> 5, c = tid & 31;
  int n = blockIdx.x * 8 + ln;                // grid exactly N/8
  int e0 = row[n], e1 = row[n + 1];

  float m00 = 0.f, m01 = 0.f;
  float m10x = 0.f, m10y = 0.f, m10z = 0.f;
  float m11x = 0.f, m11y = 0.f, m11z = 0.f;
  float m12x = 0.f, m12y = 0.f, m12z = 0.f;

  for (int e = e0; e < e1; ++e) {
    int j = idx_j[e];
    float4 xj = ((const float4*)x_ws)[(size_t)j * 32 + c];  // {x0, x1_0, x1_1, x1_2}
    float4 y  = ((const float4*)ea)[e];                     // {y0, y1_0, y1_1, y1_2}
    const unsigned short* wr = w_ws + (size_t)e * 160;
    float w0 = bf2f(wr[c]);
    float w1 = bf2f(wr[32 + c]);
    float w2 = bf2f(wr[64 + c]);
    float w3 = bf2f(wr[96 + c]);
    float w4 = bf2f(wr[128 + c]);
    m00 += w0 * xj.x * y.x;                                   // p0
    m01 += w3 * (xj.y * y.y + xj.z * y.z + xj.w * y.w);       // p3
    m10x += w1 * xj.x * y.y; m10y += w1 * xj.x * y.z; m10z += w1 * xj.x * y.w;  // p1
    m11x += w2 * xj.y * y.x; m11y += w2 * xj.z * y.x; m11z += w2 * xj.w * y.x;  // p2
    float cx = xj.z * y.w - xj.w * y.z;
    float cy = xj.w * y.y - xj.y * y.w;
    float cz = xj.y * y.z - xj.z * y.y;
    m12x += w4 * cx; m12y += w4 * cy; m12z += w4 * cz;        // p4
  }

  msg[ln][c]      = m00;
  msg[ln][32 + c] = m01;
  msg[ln][64 + (0 * 32 + c) * 3 + 0] = m10x;
  msg[ln][64 + (0 * 32 + c) * 3 + 1] = m10y;
  msg[ln][64 + (0 * 32 + c) * 3 + 2] = m10z;
  msg[ln][64 + (1 * 32 + c) * 3 + 0] = m11x;
  msg[ln][64 + (1 * 32 + c) * 3 + 1] = m11y;
  msg[ln][64 + (1 * 32 + c) * 3 + 2] = m11z;
  msg[ln][64 + (2 * 32 + c) * 3 + 0] = m12x;
  msg[ln][64 + (2 * 32 + c) * 3 + 1] = m12y;
  msg[ln][64 + (2 * 32 + c) * 3 + 2] = m12z;
  __syncthreads();

  // out0[n][d=c], out1[n][d=c][m]
  float o0 = 0.f;
#pragma unroll 4
  for (int k = 0; k < 64; ++k) o0 += msg[ln][k] * W0T[k * 33 + c];
  float o1x = 0.f, o1y = 0.f, o1z = 0.f;
#pragma unroll 4
  for (int k = 0; k < 96; ++k) {
    float wv = W1T[k * 33 + c];
    o1x += msg[ln][64 + k * 3 + 0] * wv;
    o1y += msg[ln][64 + k * 3 + 1] * wv;
    o1z += msg[ln][64 + k * 3 + 2] * wv;
  }
  float4 res = {o0 * INV8 * INV_AVG, o1x * INV_SQRT96 * INV_AVG,
                o1y * INV_SQRT96 * INV_AVG, o1z * INV_SQRT96 * INV_AVG};
  ((float4*)out_msg)[(size_t)n * 32 + c] = res;
}

extern "C" void kernel_launch(void* const* d_in, const int* in_sizes, int n_in,
                              void* d_out, int out_size, void* d_ws, size_t ws_size,
                              hipStream_t stream) {
  const float* node_attrs = (const float*)d_in[0];
  const float* node_feats = (const float*)d_in[1];
  const float* edge_attrs = (const float*)d_in[2];
  const float* edge_feats = (const float*)d_in[3];
  const float* W_first    = (const float*)d_in[4];
  const float* Wr0        = (const float*)d_in[5];
  const float* Wr1        = (const float*)d_in[6];
  const float* Wr2        = (const float*)d_in[7];
  const float* Wr3        = (const float*)d_in[8];
  const float* Ws0        = (const float*)d_in[9];
  const float* Ws1        = (const float*)d_in[10];
  const float* Wsk        = (const float*)d_in[11];
  const int*   idx_i      = (const int*)d_in[12];
  const int*   idx_j      = (const int*)d_in[13];
  float* out = (float*)d_out;

  char* ws = (char*)d_ws;
  float*          x_ws = (float*)(ws + OFF_X);
  int*            row  = (int*)(ws + OFF_ROW);
  float*          W2T  = (float*)(ws + OFF_W2T);
  unsigned short* w_ws = (unsigned short*)(ws + OFF_W);

  k_rowstart<<<(N_EDGES + 255) / 256, 256, 0, stream>>>(idx_i, row, N_EDGES, N_NODES);
  k_transpose64<<<16, 256, 0, stream>>>(Wr2, W2T);
  k_node<<<N_NODES / 8, 256, 0, stream>>>(node_attrs, node_feats, W_first, Wsk,
                                          out + 6400000, x_ws);
  k_mlp<<<(N_EDGES + 255) / 256, 256, 0, stream>>>(edge_feats, Wr0, Wr1, W2T, Wr3,
                                                   w_ws, N_EDGES);
  k_msg<<<N_NODES / 8, 256, 0, stream>>>(w_ws, x_ws, edge_attrs, idx_j, row,
                                         Ws0, Ws1, out);
}

// Round 3
// 569.036 us; speedup vs baseline: 2.2366x; 2.2170x over previous
//
#include <hip/hip_runtime.h>
#include <math.h>

#define N_NODES 50000
#define N_EDGES 600000

constexpr float RS          = 1.6765324703310907f;
constexpr float INV_SQRT8   = 0.35355339059327373f;
constexpr float INV8        = 0.125f;
constexpr float INV_SQRT320 = 0.05590169943749474f;
constexpr float INV_SQRT32  = 0.17677669529663687f;
constexpr float INV_SQRT96  = 0.10206207261596575f;
constexpr float INV_AVG     = 1.0f / 12.0f;

// ws layout (bytes)
constexpr size_t OFF_X    = 0;           // N*32 float4 = 25,600,000
constexpr size_t OFF_ROW  = 25600000;    // (N+1) int   =    200,004
constexpr size_t OFF_FRAG = 25800064;    // 40 frag-sets * 512 bf16 = 40,960
constexpr size_t OFF_W    = 25841024;    // E*160 bf16  = 192,000,000

typedef __attribute__((ext_vector_type(8))) short bfrag;   // 8 bf16 (4 VGPRs)
typedef __attribute__((ext_vector_type(4))) float ffrag;   // 4 fp32 acc

__device__ __forceinline__ float rsilu(float z) {
  return RS * z / (1.0f + __expf(-z));
}
__device__ __forceinline__ unsigned short f2bf(float x) {
  unsigned u = __float_as_uint(x);
  u += 0x7FFFu + ((u >> 16) & 1u);
  return (unsigned short)(u >> 16);
}
__device__ __forceinline__ float bf2f(unsigned short u) {
  return __uint_as_float(((unsigned)u) << 16);
}

// ---------------- CSR row offsets from sorted idx_i ----------------
__global__ __launch_bounds__(256) void k_rowstart(const int* __restrict__ idx_i,
                                                  int* __restrict__ row,
                                                  int E, int N) {
  int e = blockIdx.x * 256 + threadIdx.x;
  if (e >= E) return;
  int cur  = idx_i[e];
  int prev = (e == 0) ? -1 : idx_i[e - 1];
  for (int n = prev + 1; n <= cur; ++n) row[n] = e;
  if (e == E - 1) {
    for (int n = cur + 1; n <= N; ++n) row[n] = E;
  }
}

// ---------------- pre-pack weights into MFMA B-fragment order (bf16) -------
// frag set f (512 bf16 each), element index = (f*64 + lane)*8 + j.
// B-frag layout (16x16x32): lane holds B[k=(lane>>4)*8+j][n=lane&15] = W[n][k].
//   f 0..3   : layer1, Wr0 (64x8), K padded 8->32, ntile=f, single k-step
//   f 4..11  : layer2, Wr1 (64x64), f=4 + ntile*2 + ks
//   f 12..19 : layer3, Wr2 (64x64), f=12 + ntile*2 + ks
//   f 20..39 : layer4, Wr3 (160x64), f=20 + ntile*2 + ks
__global__ __launch_bounds__(256) void k_prep(const float* __restrict__ Wr0,
                                              const float* __restrict__ Wr1,
                                              const float* __restrict__ Wr2,
                                              const float* __restrict__ Wr3,
                                              unsigned short* __restrict__ frag) {
  int t = blockIdx.x * 256 + threadIdx.x;   // exactly 40*512 = 20480 threads
  int f    = t >> 9;
  int lane = (t >> 3) & 63;
  int j    = t & 7;
  int n16  = lane & 15, quad = lane >> 4;
  float v;
  if (f < 4) {
    int d = f * 16 + n16, k = quad * 8 + j;
    v = (k < 8) ? Wr0[d * 8 + k] : 0.f;
  } else if (f < 12) {
    int ff = f - 4, ntile = ff >> 1, ks = ff & 1;
    int d = ntile * 16 + n16, k = ks * 32 + quad * 8 + j;
    v = Wr1[d * 64 + k];
  } else if (f < 20) {
    int ff = f - 12, ntile = ff >> 1, ks = ff & 1;
    int d = ntile * 16 + n16, k = ks * 32 + quad * 8 + j;
    v = Wr2[d * 64 + k];
  } else {
    int ff = f - 20, ntile = ff >> 1, ks = ff & 1;
    int d = ntile * 16 + n16, k = ks * 32 + quad * 8 + j;
    v = Wr3[d * 64 + k];
  }
  frag[t] = f2bf(v);
}

// ---------------- per-node: sc (skip) + x (first linear) ----------------
__global__ __launch_bounds__(256) void k_node(const float* __restrict__ attrs,
                                              const float* __restrict__ feats,
                                              const float* __restrict__ Wf,
                                              const float* __restrict__ Wsk,
                                              float* __restrict__ out_sc,
                                              float* __restrict__ x_ws) {
  int t = blockIdx.x * 256 + threadIdx.x;   // exactly N*32 threads
  int n = t >> 5, w = t & 31;
  float a[10];
#pragma unroll
  for (int v = 0; v < 10; ++v) a[v] = attrs[n * 10 + v];
  float scm0 = 0.f, scm1 = 0.f, scm2 = 0.f, scm3 = 0.f;
  float x0 = 0.f, x1 = 0.f, x2 = 0.f, x3 = 0.f;
  const float4* f4 = (const float4*)feats + (size_t)n * 32;
#pragma unroll 4
  for (int c = 0; c < 32; ++c) {
    float4 f = f4[c];
    float a0 = 0.f, a1 = 0.f;
#pragma unroll
    for (int v = 0; v < 10; ++v) {
      a0 += a[v] * Wsk[(c * 10 + v) * 32 + w];            // W_skip[0][c][v][w]
      a1 += a[v] * Wsk[((32 + c) * 10 + v) * 32 + w];     // W_skip[1][c][v][w]
    }
    scm0 += f.x * a0; scm1 += f.y * a1; scm2 += f.z * a1; scm3 += f.w * a1;
    float wf0 = Wf[w * 32 + c];            // W_first[0][w][c]
    float wf1 = Wf[1024 + w * 32 + c];     // W_first[1][w][c]
    x0 += f.x * wf0; x1 += f.y * wf1; x2 += f.z * wf1; x3 += f.w * wf1;
  }
  float4 sc = {scm0 * INV_SQRT320, scm1 * INV_SQRT320,
               scm2 * INV_SQRT320, scm3 * INV_SQRT320};
  float4 xx = {x0 * INV_SQRT32, x1 * INV_SQRT32, x2 * INV_SQRT32, x3 * INV_SQRT32};
  ((float4*)out_sc)[(size_t)n * 32 + w] = sc;
  ((float4*)x_ws)[(size_t)n * 32 + w]   = xx;
}

// ---------------- per-edge 4-layer MLP via MFMA -> w (bf16, E x 160) -------
// Block = 128 edges, 4 waves; wave owns 32 rows end-to-end (no barriers).
// Activations round-trip LDS in bf16; weights come pre-packed from k_prep.
// LDS stride 168 bf16 (336 B): A-frag b128 reads land 2 lanes/bank (free).
#define MLP_M 128
__global__ __launch_bounds__(256) void k_mlp(const float* __restrict__ ef,
                                             const unsigned short* __restrict__ frag,
                                             unsigned short* __restrict__ w_out,
                                             int E) {
  __shared__ __align__(16) unsigned short H[4][32][168];
  int tid = threadIdx.x;
  int wave = tid >> 6, lane = tid & 63;
  int quad = lane >> 4, l16 = lane & 15;
  int m0 = blockIdx.x * MLP_M + wave * 32;   // wave's first edge row
  unsigned short (*Hw)[168] = H[wave];

  // ---- layer 1: A = edge_feats rows (K=8 zero-padded to 32) ----
  bfrag a1[2];
#pragma unroll
  for (int mt = 0; mt < 2; ++mt) {
    float vals[8] = {0.f, 0.f, 0.f, 0.f, 0.f, 0.f, 0.f, 0.f};
    if (quad == 0) {
      int r = m0 + mt * 16 + l16;
      if (r > E - 1) r = E - 1;
      const float4* p = (const float4*)(ef + (size_t)r * 8);
      float4 u0 = p[0], u1 = p[1];
      vals[0] = u0.x; vals[1] = u0.y; vals[2] = u0.z; vals[3] = u0.w;
      vals[4] = u1.x; vals[5] = u1.y; vals[6] = u1.z; vals[7] = u1.w;
    }
    union { unsigned short s[8]; bfrag v; } pk;
#pragma unroll
    for (int j = 0; j < 8; ++j) pk.s[j] = f2bf(vals[j]);
    a1[mt] = pk.v;
  }
#pragma unroll
  for (int nt = 0; nt < 4; ++nt) {
    const bfrag* bp = (const bfrag*)(frag + ((size_t)(nt) * 64 + lane) * 8);
    bfrag b = *bp;
    ffrag acc0 = {0.f, 0.f, 0.f, 0.f}, acc1 = acc0;
    acc0 = __builtin_amdgcn_mfma_f32_16x16x32_bf16(a1[0], b, acc0, 0, 0, 0);
    acc1 = __builtin_amdgcn_mfma_f32_16x16x32_bf16(a1[1], b, acc1, 0, 0, 0);
#pragma unroll
    for (int r = 0; r < 4; ++r) {
      Hw[0 * 16 + quad * 4 + r][nt * 16 + l16] = f2bf(rsilu(acc0[r] * INV_SQRT8));
      Hw[1 * 16 + quad * 4 + r][nt * 16 + l16] = f2bf(rsilu(acc1[r] * INV_SQRT8));
    }
  }

  // ---- layers 2,3 (N=64), layer 4 (N=160) ----
  bfrag A[2][2];
#pragma unroll 1
  for (int L = 0; L < 2; ++L) {           // layers 2 and 3
    int fbase = 4 + L * 8;
#pragma unroll
    for (int mt = 0; mt < 2; ++mt)
#pragma unroll
      for (int ks = 0; ks < 2; ++ks)
        A[mt][ks] = *(const bfrag*)&Hw[mt * 16 + l16][ks * 32 + quad * 8];
#pragma unroll
    for (int nt = 0; nt < 4; ++nt) {
      ffrag acc0 = {0.f, 0.f, 0.f, 0.f}, acc1 = acc0;
#pragma unroll
      for (int ks = 0; ks < 2; ++ks) {
        bfrag b = *(const bfrag*)(frag + ((size_t)(fbase + nt * 2 + ks) * 64 + lane) * 8);
        acc0 = __builtin_amdgcn_mfma_f32_16x16x32_bf16(A[0][ks], b, acc0, 0, 0, 0);
        acc1 = __builtin_amdgcn_mfma_f32_16x16x32_bf16(A[1][ks], b, acc1, 0, 0, 0);
      }
#pragma unroll
      for (int r = 0; r < 4; ++r) {
        Hw[0 * 16 + quad * 4 + r][nt * 16 + l16] = f2bf(rsilu(acc0[r] * INV8));
        Hw[1 * 16 + quad * 4 + r][nt * 16 + l16] = f2bf(rsilu(acc1[r] * INV8));
      }
    }
  }

  // layer 4: w = h3 @ Wr3^T / 8, no activation; stage bf16 rows in LDS
#pragma unroll
  for (int mt = 0; mt < 2; ++mt)
#pragma unroll
    for (int ks = 0; ks < 2; ++ks)
      A[mt][ks] = *(const bfrag*)&Hw[mt * 16 + l16][ks * 32 + quad * 8];
#pragma unroll 2
  for (int nt = 0; nt < 10; ++nt) {
    ffrag acc0 = {0.f, 0.f, 0.f, 0.f}, acc1 = acc0;
#pragma unroll
    for (int ks = 0; ks < 2; ++ks) {
      bfrag b = *(const bfrag*)(frag + ((size_t)(20 + nt * 2 + ks) * 64 + lane) * 8);
      acc0 = __builtin_amdgcn_mfma_f32_16x16x32_bf16(A[0][ks], b, acc0, 0, 0, 0);
      acc1 = __builtin_amdgcn_mfma_f32_16x16x32_bf16(A[1][ks], b, acc1, 0, 0, 0);
    }
#pragma unroll
    for (int r = 0; r < 4; ++r) {
      Hw[0 * 16 + quad * 4 + r][nt * 16 + l16] = f2bf(acc0[r] * INV8);
      Hw[1 * 16 + quad * 4 + r][nt * 16 + l16] = f2bf(acc1[r] * INV8);
    }
  }

  // flush: 32 rows x 160 bf16 -> global, 16 B chunks, coalesced-ish
#pragma unroll 2
  for (int it = 0; it < 10; ++it) {
    int c = it * 64 + lane;            // 0..639
    int row = c / 20, off = c % 20;
    int grow = m0 + row;
    uint4 v = *(const uint4*)&Hw[row][off * 8];
    if (grow < E)
      *(uint4*)(w_out + (size_t)grow * 160 + off * 8) = v;
  }
}

// ---------------- per-node message accumulation + W_second contraction ----------------
__global__ __launch_bounds__(256) void k_msg(const unsigned short* __restrict__ w_ws,
                                             const float* __restrict__ x_ws,
                                             const float* __restrict__ ea,
                                             const int* __restrict__ idx_j,
                                             const int* __restrict__ row,
                                             const float* __restrict__ Ws0,
                                             const float* __restrict__ Ws1,
                                             float* __restrict__ out_msg) {
  __shared__ float msg[8][353];     // 352 comps padded (353%32==1 -> conflict-free)
  __shared__ float W0T[64 * 33];    // [k*33+d]
  __shared__ float W1T[96 * 33];

  int tid = threadIdx.x;
  for (int t = tid; t < 2048; t += 256) {     // Ws0 (32x64) -> W0T[k][d]
    int d = t >> 6, k = t & 63;
    W0T[k * 33 + d] = Ws0[t];
  }
  for (int t = tid; t < 3072; t += 256) {     // Ws1 (32x96) -> W1T[k][d]
    int d = t / 96, k = t % 96;
    W1T[k * 33 + d] = Ws1[t];
  }

  int ln = tid >> 5, c = tid & 31;
  int n = blockIdx.x * 8 + ln;                // grid exactly N/8
  int e0 = row[n], e1 = row[n + 1];

  float m00 = 0.f, m01 = 0.f;
  float m10x = 0.f, m10y = 0.f, m10z = 0.f;
  float m11x = 0.f, m11y = 0.f, m11z = 0.f;
  float m12x = 0.f, m12y = 0.f, m12z = 0.f;

  for (int e = e0; e < e1; ++e) {
    int j = idx_j[e];
    float4 xj = ((const float4*)x_ws)[(size_t)j * 32 + c];  // {x0, x1_0, x1_1, x1_2}
    float4 y  = ((const float4*)ea)[e];                     // {y0, y1_0, y1_1, y1_2}
    const unsigned short* wr = w_ws + (size_t)e * 160;
    float w0 = bf2f(wr[c]);
    float w1 = bf2f(wr[32 + c]);
    float w2 = bf2f(wr[64 + c]);
    float w3 = bf2f(wr[96 + c]);
    float w4 = bf2f(wr[128 + c]);
    m00 += w0 * xj.x * y.x;                                   // p0
    m01 += w3 * (xj.y * y.y + xj.z * y.z + xj.w * y.w);       // p3
    m10x += w1 * xj.x * y.y; m10y += w1 * xj.x * y.z; m10z += w1 * xj.x * y.w;  // p1
    m11x += w2 * xj.y * y.x; m11y += w2 * xj.z * y.x; m11z += w2 * xj.w * y.x;  // p2
    float cx = xj.z * y.w - xj.w * y.z;
    float cy = xj.w * y.y - xj.y * y.w;
    float cz = xj.y * y.z - xj.z * y.y;
    m12x += w4 * cx; m12y += w4 * cy; m12z += w4 * cz;        // p4
  }

  msg[ln][c]      = m00;
  msg[ln][32 + c] = m01;
  msg[ln][64 + (0 * 32 + c) * 3 + 0] = m10x;
  msg[ln][64 + (0 * 32 + c) * 3 + 1] = m10y;
  msg[ln][64 + (0 * 32 + c) * 3 + 2] = m10z;
  msg[ln][64 + (1 * 32 + c) * 3 + 0] = m11x;
  msg[ln][64 + (1 * 32 + c) * 3 + 1] = m11y;
  msg[ln][64 + (1 * 32 + c) * 3 + 2] = m11z;
  msg[ln][64 + (2 * 32 + c) * 3 + 0] = m12x;
  msg[ln][64 + (2 * 32 + c) * 3 + 1] = m12y;
  msg[ln][64 + (2 * 32 + c) * 3 + 2] = m12z;
  __syncthreads();

  // out0[n][d=c], out1[n][d=c][m]
  float o0 = 0.f;
#pragma unroll 4
  for (int k = 0; k < 64; ++k) o0 += msg[ln][k] * W0T[k * 33 + c];
  float o1x = 0.f, o1y = 0.f, o1z = 0.f;
#pragma unroll 4
  for (int k = 0; k < 96; ++k) {
    float wv = W1T[k * 33 + c];
    o1x += msg[ln][64 + k * 3 + 0] * wv;
    o1y += msg[ln][64 + k * 3 + 1] * wv;
    o1z += msg[ln][64 + k * 3 + 2] * wv;
  }
  float4 res = {o0 * INV8 * INV_AVG, o1x * INV_SQRT96 * INV_AVG,
                o1y * INV_SQRT96 * INV_AVG, o1z * INV_SQRT96 * INV_AVG};
  ((float4*)out_msg)[(size_t)n * 32 + c] = res;
}

extern "C" void kernel_launch(void* const* d_in, const int* in_sizes, int n_in,
                              void* d_out, int out_size, void* d_ws, size_t ws_size,
                              hipStream_t stream) {
  const float* node_attrs = (const float*)d_in[0];
  const float* node_feats = (const float*)d_in[1];
  const float* edge_attrs = (const float*)d_in[2];
  const float* edge_feats = (const float*)d_in[3];
  const float* W_first    = (const float*)d_in[4];
  const float* Wr0        = (const float*)d_in[5];
  const float* Wr1        = (const float*)d_in[6];
  const float* Wr2        = (const float*)d_in[7];
  const float* Wr3        = (const float*)d_in[8];
  const float* Ws0        = (const float*)d_in[9];
  const float* Ws1        = (const float*)d_in[10];
  const float* Wsk        = (const float*)d_in[11];
  const int*   idx_i      = (const int*)d_in[12];
  const int*   idx_j      = (const int*)d_in[13];
  float* out = (float*)d_out;

  char* ws = (char*)d_ws;
  float*          x_ws  = (float*)(ws + OFF_X);
  int*            rowp  = (int*)(ws + OFF_ROW);
  unsigned short* fragp = (unsigned short*)(ws + OFF_FRAG);
  unsigned short* w_ws  = (unsigned short*)(ws + OFF_W);

  k_rowstart<<<(N_EDGES + 255) / 256, 256, 0, stream>>>(idx_i, rowp, N_EDGES, N_NODES);
  k_prep<<<80, 256, 0, stream>>>(Wr0, Wr1, Wr2, Wr3, fragp);
  k_node<<<N_NODES / 8, 256, 0, stream>>>(node_attrs, node_feats, W_first, Wsk,
                                          out + 6400000, x_ws);
  k_mlp<<<(N_EDGES + MLP_M - 1) / MLP_M, 256, 0, stream>>>(edge_feats, fragp,
                                                           w_ws, N_EDGES);
  k_msg<<<N_NODES / 8, 256, 0, stream>>>(w_ws, x_ws, edge_attrs, idx_j, rowp,
                                         Ws0, Ws1, out);
}

// Round 4
// 414.329 us; speedup vs baseline: 3.0717x; 1.3734x over previous
//
#include <hip/hip_runtime.h>
#include <math.h>

#define N_NODES 50000
#define N_EDGES 600000

constexpr float RS          = 1.6765324703310907f;
constexpr float INV_SQRT8   = 0.35355339059327373f;
constexpr float INV8        = 0.125f;
constexpr float INV_SQRT320 = 0.05590169943749474f;
constexpr float INV_SQRT32  = 0.17677669529663687f;
constexpr float INV_SQRT96  = 0.10206207261596575f;
constexpr float INV_AVG     = 1.0f / 12.0f;

// ws layout (bytes)
constexpr size_t OFF_X     = 0;           // N*32 float4 = 25,600,000
constexpr size_t OFF_ROW   = 25600000;    // (N+1) int   =    200,004
constexpr size_t OFF_FRAG  = 25800064;    // 40 frag-sets * 512 bf16 = 40,960
constexpr size_t OFF_FRAG2 = 25841024;    // 88 frag-sets * 512 bf16 = 90,112
constexpr size_t OFF_W     = 25931136;    // E*160 bf16  = 192,000,000

typedef __attribute__((ext_vector_type(8))) short bfrag;   // 8 bf16 (4 VGPRs)
typedef __attribute__((ext_vector_type(4))) float ffrag;   // 4 fp32 acc

__device__ __forceinline__ float rsilu(float z) {
  return RS * z / (1.0f + __expf(-z));
}
__device__ __forceinline__ unsigned short f2bf(float x) {
  unsigned u = __float_as_uint(x);
  u += 0x7FFFu + ((u >> 16) & 1u);
  return (unsigned short)(u >> 16);
}
__device__ __forceinline__ float bf2f(unsigned short u) {
  return __uint_as_float(((unsigned)u) << 16);
}

// ---------------- CSR row offsets from sorted idx_i ----------------
__global__ __launch_bounds__(256) void k_rowstart(const int* __restrict__ idx_i,
                                                  int* __restrict__ row,
                                                  int E, int N) {
  int e = blockIdx.x * 256 + threadIdx.x;
  if (e >= E) return;
  int cur  = idx_i[e];
  int prev = (e == 0) ? -1 : idx_i[e - 1];
  for (int n = prev + 1; n <= cur; ++n) row[n] = e;
  if (e == E - 1) {
    for (int n = cur + 1; n <= N; ++n) row[n] = E;
  }
}

// ---------------- pre-pack MLP weights into MFMA B-fragment order ----------
// frag set f (512 bf16 each), element index = (f*64 + lane)*8 + j.
// B-frag layout (16x16x32): lane holds B[k=(lane>>4)*8+j][n=lane&15] = W[n][k].
__global__ __launch_bounds__(256) void k_prep(const float* __restrict__ Wr0,
                                              const float* __restrict__ Wr1,
                                              const float* __restrict__ Wr2,
                                              const float* __restrict__ Wr3,
                                              unsigned short* __restrict__ frag) {
  int t = blockIdx.x * 256 + threadIdx.x;   // exactly 40*512 = 20480 threads
  int f    = t >> 9;
  int lane = (t >> 3) & 63;
  int j    = t & 7;
  int n16  = lane & 15, quad = lane >> 4;
  float v;
  if (f < 4) {
    int d = f * 16 + n16, k = quad * 8 + j;
    v = (k < 8) ? Wr0[d * 8 + k] : 0.f;
  } else if (f < 12) {
    int ff = f - 4, ntile = ff >> 1, ks = ff & 1;
    int d = ntile * 16 + n16, k = ks * 32 + quad * 8 + j;
    v = Wr1[d * 64 + k];
  } else if (f < 20) {
    int ff = f - 12, ntile = ff >> 1, ks = ff & 1;
    int d = ntile * 16 + n16, k = ks * 32 + quad * 8 + j;
    v = Wr2[d * 64 + k];
  } else {
    int ff = f - 20, ntile = ff >> 1, ks = ff & 1;
    int d = ntile * 16 + n16, k = ks * 32 + quad * 8 + j;
    v = Wr3[d * 64 + k];
  }
  frag[t] = f2bf(v);
}

// ---------------- pre-pack node weights: B2 [K=352][128 cols], frag order ---
// K-order: k = v*32 + c for k<320 (v=k>>5, c=k&31); k>=320 -> c = k-320.
// cols 0..31: sc path0 (Wsk[0][c][v][w] * 1/sqrt320), 32..63: sc path1,
// cols 64..95: x path0 (Wf[0][d][c] * 1/sqrt32),    96..127: x path1.
// frag f = ks*8 + nt (ks 0..10, nt 0..7); 88 frags.
__global__ __launch_bounds__(256) void k_prep2(const float* __restrict__ Wsk,
                                               const float* __restrict__ Wf,
                                               unsigned short* __restrict__ frag2) {
  int t = blockIdx.x * 256 + threadIdx.x;   // exactly 88*512 = 45056 threads
  int f    = t >> 9;
  int lane = (t >> 3) & 63;
  int j    = t & 7;
  int n16  = lane & 15, quad = lane >> 4;
  int ks = f >> 3, nt = f & 7;
  int k   = ks * 32 + quad * 8 + j;
  int col = nt * 16 + n16;
  float v = 0.f;
  if (k < 320) {
    int vv = k >> 5, c = k & 31;
    if (col < 32)       v = Wsk[(c * 10 + vv) * 32 + col] * INV_SQRT320;
    else if (col < 64)  v = Wsk[((32 + c) * 10 + vv) * 32 + (col - 32)] * INV_SQRT320;
  } else {
    int c = k - 320;
    if (col >= 96)      v = Wf[1024 + (col - 96) * 32 + c] * INV_SQRT32;
    else if (col >= 64) v = Wf[(col - 64) * 32 + c] * INV_SQRT32;
  }
  frag2[t] = f2bf(v);
}

// ---------------- per-node sc + x via MFMA ----------------
// Wave = 8 nodes (2 mtiles of 16 rows = (node,m)); rows: l16 -> (node=l16>>2, m=l16&3).
// A[row][k]: k<320 -> attrs[node][k>>5] * feats[node][k&31][m]; k>=320 -> feats[node][k-320][m].
// Per ks the A-frag is attrs[ks] * (fixed feats frag) -- 1 scale+pack per step.
__global__ __launch_bounds__(256) void k_node_mfma(const float* __restrict__ attrs,
                                                   const float* __restrict__ feats,
                                                   const unsigned short* __restrict__ frag2,
                                                   float* __restrict__ out_sc,
                                                   float* __restrict__ x_ws) {
  int tid = threadIdx.x;
  int wave = tid >> 6, lane = tid & 63;
  int quad = lane >> 4, l16 = lane & 15;
  int nb = blockIdx.x * 32 + wave * 8;

  float featsF[2][8];
  float a[2][10];
#pragma unroll
  for (int mt = 0; mt < 2; ++mt) {
    int nodeA = nb + mt * 4 + (l16 >> 2);
    if (nodeA > N_NODES - 1) nodeA = N_NODES - 1;
    int m = l16 & 3;
#pragma unroll
    for (int j = 0; j < 8; ++j)
      featsF[mt][j] = feats[(size_t)nodeA * 128 + (quad * 8 + j) * 4 + m];
#pragma unroll
    for (int v = 0; v < 10; ++v) a[mt][v] = attrs[nodeA * 10 + v];
  }

  ffrag acc[2][8];
#pragma unroll
  for (int mt = 0; mt < 2; ++mt)
#pragma unroll
    for (int nt = 0; nt < 8; ++nt) acc[mt][nt] = (ffrag){0.f, 0.f, 0.f, 0.f};

#pragma unroll
  for (int ks = 0; ks < 11; ++ks) {
    bfrag Ab[2];
#pragma unroll
    for (int mt = 0; mt < 2; ++mt) {
      union { unsigned short s8[8]; bfrag v; } pk;
#pragma unroll
      for (int j = 0; j < 8; ++j) {
        float val = (ks < 10) ? a[mt][ks] * featsF[mt][j] : featsF[mt][j];
        pk.s8[j] = f2bf(val);
      }
      Ab[mt] = pk.v;
    }
#pragma unroll
    for (int nt = 0; nt < 8; ++nt) {
      bfrag B = *(const bfrag*)(frag2 + ((size_t)(ks * 8 + nt) * 64 + lane) * 8);
      acc[0][nt] = __builtin_amdgcn_mfma_f32_16x16x32_bf16(Ab[0], B, acc[0][nt], 0, 0, 0);
      acc[1][nt] = __builtin_amdgcn_mfma_f32_16x16x32_bf16(Ab[1], B, acc[1][nt], 0, 0, 0);
    }
  }

  // C/D: row = quad*4+r -> (node = quad, m = r); col = nt*16+l16.
#pragma unroll
  for (int mt = 0; mt < 2; ++mt) {
    int node = nb + mt * 4 + quad;
    if (node < N_NODES) {
      float4 sc0 = {acc[mt][0][0], acc[mt][2][1], acc[mt][2][2], acc[mt][2][3]};
      float4 sc1 = {acc[mt][1][0], acc[mt][3][1], acc[mt][3][2], acc[mt][3][3]};
      float4 x0  = {acc[mt][4][0], acc[mt][6][1], acc[mt][6][2], acc[mt][6][3]};
      float4 x1  = {acc[mt][5][0], acc[mt][7][1], acc[mt][7][2], acc[mt][7][3]};
      ((float4*)out_sc)[(size_t)node * 32 + l16]      = sc0;
      ((float4*)out_sc)[(size_t)node * 32 + 16 + l16] = sc1;
      ((float4*)x_ws)[(size_t)node * 32 + l16]        = x0;
      ((float4*)x_ws)[(size_t)node * 32 + 16 + l16]   = x1;
    }
  }
}

// ---------------- per-edge 4-layer MLP via MFMA -> w (bf16, E x 160) -------
#define MLP_M 128
__global__ __launch_bounds__(256) void k_mlp(const float* __restrict__ ef,
                                             const unsigned short* __restrict__ frag,
                                             unsigned short* __restrict__ w_out,
                                             int E) {
  __shared__ __align__(16) unsigned short H[4][32][168];
  int tid = threadIdx.x;
  int wave = tid >> 6, lane = tid & 63;
  int quad = lane >> 4, l16 = lane & 15;
  int m0 = blockIdx.x * MLP_M + wave * 32;   // wave's first edge row
  unsigned short (*Hw)[168] = H[wave];

  // ---- layer 1: A = edge_feats rows (K=8 zero-padded to 32) ----
  bfrag a1[2];
#pragma unroll
  for (int mt = 0; mt < 2; ++mt) {
    float vals[8] = {0.f, 0.f, 0.f, 0.f, 0.f, 0.f, 0.f, 0.f};
    if (quad == 0) {
      int r = m0 + mt * 16 + l16;
      if (r > E - 1) r = E - 1;
      const float4* p = (const float4*)(ef + (size_t)r * 8);
      float4 u0 = p[0], u1 = p[1];
      vals[0] = u0.x; vals[1] = u0.y; vals[2] = u0.z; vals[3] = u0.w;
      vals[4] = u1.x; vals[5] = u1.y; vals[6] = u1.z; vals[7] = u1.w;
    }
    union { unsigned short s[8]; bfrag v; } pk;
#pragma unroll
    for (int j = 0; j < 8; ++j) pk.s[j] = f2bf(vals[j]);
    a1[mt] = pk.v;
  }
#pragma unroll
  for (int nt = 0; nt < 4; ++nt) {
    const bfrag* bp = (const bfrag*)(frag + ((size_t)(nt) * 64 + lane) * 8);
    bfrag b = *bp;
    ffrag acc0 = {0.f, 0.f, 0.f, 0.f}, acc1 = acc0;
    acc0 = __builtin_amdgcn_mfma_f32_16x16x32_bf16(a1[0], b, acc0, 0, 0, 0);
    acc1 = __builtin_amdgcn_mfma_f32_16x16x32_bf16(a1[1], b, acc1, 0, 0, 0);
#pragma unroll
    for (int r = 0; r < 4; ++r) {
      Hw[0 * 16 + quad * 4 + r][nt * 16 + l16] = f2bf(rsilu(acc0[r] * INV_SQRT8));
      Hw[1 * 16 + quad * 4 + r][nt * 16 + l16] = f2bf(rsilu(acc1[r] * INV_SQRT8));
    }
  }

  // ---- layers 2,3 (N=64), layer 4 (N=160) ----
  bfrag A[2][2];
#pragma unroll 1
  for (int L = 0; L < 2; ++L) {           // layers 2 and 3
    int fbase = 4 + L * 8;
#pragma unroll
    for (int mt = 0; mt < 2; ++mt)
#pragma unroll
      for (int ks = 0; ks < 2; ++ks)
        A[mt][ks] = *(const bfrag*)&Hw[mt * 16 + l16][ks * 32 + quad * 8];
#pragma unroll
    for (int nt = 0; nt < 4; ++nt) {
      ffrag acc0 = {0.f, 0.f, 0.f, 0.f}, acc1 = acc0;
#pragma unroll
      for (int ks = 0; ks < 2; ++ks) {
        bfrag b = *(const bfrag*)(frag + ((size_t)(fbase + nt * 2 + ks) * 64 + lane) * 8);
        acc0 = __builtin_amdgcn_mfma_f32_16x16x32_bf16(A[0][ks], b, acc0, 0, 0, 0);
        acc1 = __builtin_amdgcn_mfma_f32_16x16x32_bf16(A[1][ks], b, acc1, 0, 0, 0);
      }
#pragma unroll
      for (int r = 0; r < 4; ++r) {
        Hw[0 * 16 + quad * 4 + r][nt * 16 + l16] = f2bf(rsilu(acc0[r] * INV8));
        Hw[1 * 16 + quad * 4 + r][nt * 16 + l16] = f2bf(rsilu(acc1[r] * INV8));
      }
    }
  }

  // layer 4: w = h3 @ Wr3^T / 8, no activation; stage bf16 rows in LDS
#pragma unroll
  for (int mt = 0; mt < 2; ++mt)
#pragma unroll
    for (int ks = 0; ks < 2; ++ks)
      A[mt][ks] = *(const bfrag*)&Hw[mt * 16 + l16][ks * 32 + quad * 8];
#pragma unroll 2
  for (int nt = 0; nt < 10; ++nt) {
    ffrag acc0 = {0.f, 0.f, 0.f, 0.f}, acc1 = acc0;
#pragma unroll
    for (int ks = 0; ks < 2; ++ks) {
      bfrag b = *(const bfrag*)(frag + ((size_t)(20 + nt * 2 + ks) * 64 + lane) * 8);
      acc0 = __builtin_amdgcn_mfma_f32_16x16x32_bf16(A[0][ks], b, acc0, 0, 0, 0);
      acc1 = __builtin_amdgcn_mfma_f32_16x16x32_bf16(A[1][ks], b, acc1, 0, 0, 0);
    }
#pragma unroll
    for (int r = 0; r < 4; ++r) {
      Hw[0 * 16 + quad * 4 + r][nt * 16 + l16] = f2bf(acc0[r] * INV8);
      Hw[1 * 16 + quad * 4 + r][nt * 16 + l16] = f2bf(acc1[r] * INV8);
    }
  }

  // flush: 32 rows x 160 bf16 -> global, 16 B chunks
#pragma unroll 2
  for (int it = 0; it < 10; ++it) {
    int c = it * 64 + lane;            // 0..639
    int row = c / 20, off = c % 20;
    int grow = m0 + row;
    uint4 v = *(const uint4*)&Hw[row][off * 8];
    if (grow < E)
      *(uint4*)(w_out + (size_t)grow * 160 + off * 8) = v;
  }
}

// ---------------- per-node message accumulation + W_second contraction ----------------
__global__ __launch_bounds__(256) void k_msg(const unsigned short* __restrict__ w_ws,
                                             const float* __restrict__ x_ws,
                                             const float* __restrict__ ea,
                                             const int* __restrict__ idx_j,
                                             const int* __restrict__ row,
                                             const float* __restrict__ Ws0,
                                             const float* __restrict__ Ws1,
                                             float* __restrict__ out_msg) {
  __shared__ float msg[8][353];     // 352 comps padded (353%32==1 -> conflict-free)
  __shared__ float W0T[64 * 33];    // [k*33+d]
  __shared__ float W1T[96 * 33];

  int tid = threadIdx.x;
  for (int t = tid; t < 2048; t += 256) {     // Ws0 (32x64) -> W0T[k][d]
    int d = t >> 6, k = t & 63;
    W0T[k * 33 + d] = Ws0[t];
  }
  for (int t = tid; t < 3072; t += 256) {     // Ws1 (32x96) -> W1T[k][d]
    int d = t / 96, k = t % 96;
    W1T[k * 33 + d] = Ws1[t];
  }

  int ln = tid >> 5, c = tid & 31;
  int n = blockIdx.x * 8 + ln;                // grid exactly N/8
  int e0 = row[n], e1 = row[n + 1];

  float m00 = 0.f, m01 = 0.f;
  float m10x = 0.f, m10y = 0.f, m10z = 0.f;
  float m11x = 0.f, m11y = 0.f, m11z = 0.f;
  float m12x = 0.f, m12y = 0.f, m12z = 0.f;

  for (int e = e0; e < e1; ++e) {
    int j = idx_j[e];
    float4 xj = ((const float4*)x_ws)[(size_t)j * 32 + c];  // {x0, x1_0, x1_1, x1_2}
    float4 y  = ((const float4*)ea)[e];                     // {y0, y1_0, y1_1, y1_2}
    const unsigned short* wr = w_ws + (size_t)e * 160;
    float w0 = bf2f(wr[c]);
    float w1 = bf2f(wr[32 + c]);
    float w2 = bf2f(wr[64 + c]);
    float w3 = bf2f(wr[96 + c]);
    float w4 = bf2f(wr[128 + c]);
    m00 += w0 * xj.x * y.x;                                   // p0
    m01 += w3 * (xj.y * y.y + xj.z * y.z + xj.w * y.w);       // p3
    m10x += w1 * xj.x * y.y; m10y += w1 * xj.x * y.z; m10z += w1 * xj.x * y.w;  // p1
    m11x += w2 * xj.y * y.x; m11y += w2 * xj.z * y.x; m11z += w2 * xj.w * y.x;  // p2
    float cx = xj.z * y.w - xj.w * y.z;
    float cy = xj.w * y.y - xj.y * y.w;
    float cz = xj.y * y.z - xj.z * y.y;
    m12x += w4 * cx; m12y += w4 * cy; m12z += w4 * cz;        // p4
  }

  msg[ln][c]      = m00;
  msg[ln][32 + c] = m01;
  msg[ln][64 + (0 * 32 + c) * 3 + 0] = m10x;
  msg[ln][64 + (0 * 32 + c) * 3 + 1] = m10y;
  msg[ln][64 + (0 * 32 + c) * 3 + 2] = m10z;
  msg[ln][64 + (1 * 32 + c) * 3 + 0] = m11x;
  msg[ln][64 + (1 * 32 + c) * 3 + 1] = m11y;
  msg[ln][64 + (1 * 32 + c) * 3 + 2] = m11z;
  msg[ln][64 + (2 * 32 + c) * 3 + 0] = m12x;
  msg[ln][64 + (2 * 32 + c) * 3 + 1] = m12y;
  msg[ln][64 + (2 * 32 + c) * 3 + 2] = m12z;
  __syncthreads();

  // out0[n][d=c], out1[n][d=c][m]
  float o0 = 0.f;
#pragma unroll 4
  for (int k = 0; k < 64; ++k) o0 += msg[ln][k] * W0T[k * 33 + c];
  float o1x = 0.f, o1y = 0.f, o1z = 0.f;
#pragma unroll 4
  for (int k = 0; k < 96; ++k) {
    float wv = W1T[k * 33 + c];
    o1x += msg[ln][64 + k * 3 + 0] * wv;
    o1y += msg[ln][64 + k * 3 + 1] * wv;
    o1z += msg[ln][64 + k * 3 + 2] * wv;
  }
  float4 res = {o0 * INV8 * INV_AVG, o1x * INV_SQRT96 * INV_AVG,
                o1y * INV_SQRT96 * INV_AVG, o1z * INV_SQRT96 * INV_AVG};
  ((float4*)out_msg)[(size_t)n * 32 + c] = res;
}

extern "C" void kernel_launch(void* const* d_in, const int* in_sizes, int n_in,
                              void* d_out, int out_size, void* d_ws, size_t ws_size,
                              hipStream_t stream) {
  const float* node_attrs = (const float*)d_in[0];
  const float* node_feats = (const float*)d_in[1];
  const float* edge_attrs = (const float*)d_in[2];
  const float* edge_feats = (const float*)d_in[3];
  const float* W_first    = (const float*)d_in[4];
  const float* Wr0        = (const float*)d_in[5];
  const float* Wr1        = (const float*)d_in[6];
  const float* Wr2        = (const float*)d_in[7];
  const float* Wr3        = (const float*)d_in[8];
  const float* Ws0        = (const float*)d_in[9];
  const float* Ws1        = (const float*)d_in[10];
  const float* Wsk        = (const float*)d_in[11];
  const int*   idx_i      = (const int*)d_in[12];
  const int*   idx_j      = (const int*)d_in[13];
  float* out = (float*)d_out;

  char* ws = (char*)d_ws;
  float*          x_ws   = (float*)(ws + OFF_X);
  int*            rowp   = (int*)(ws + OFF_ROW);
  unsigned short* fragp  = (unsigned short*)(ws + OFF_FRAG);
  unsigned short* frag2p = (unsigned short*)(ws + OFF_FRAG2);
  unsigned short* w_ws   = (unsigned short*)(ws + OFF_W);

  k_rowstart<<<(N_EDGES + 255) / 256, 256, 0, stream>>>(idx_i, rowp, N_EDGES, N_NODES);
  k_prep<<<80, 256, 0, stream>>>(Wr0, Wr1, Wr2, Wr3, fragp);
  k_prep2<<<176, 256, 0, stream>>>(Wsk, W_first, frag2p);
  k_node_mfma<<<(N_NODES + 31) / 32, 256, 0, stream>>>(node_attrs, node_feats,
                                                       frag2p, out + 6400000, x_ws);
  k_mlp<<<(N_EDGES + MLP_M - 1) / MLP_M, 256, 0, stream>>>(edge_feats, fragp,
                                                           w_ws, N_EDGES);
  k_msg<<<N_NODES / 8, 256, 0, stream>>>(w_ws, x_ws, edge_attrs, idx_j, rowp,
                                         Ws0, Ws1, out);
}